// Round 7
// baseline (54.262 us; speedup 1.0000x reference)
//
#include <hip/hip_runtime.h>
#include <hip/hip_cooperative_groups.h>

namespace cg = cooperative_groups;

#define N   16384
#define M   64        // Fourier modes
#define JB  128       // j-blocks per array (phase 1)
#define JSL 128       // j's per phase-1 block
#define GB  256       // grid blocks
#define I2  64        // i's per block (phase 2)

// rank_i = 1 + N/2 + 0.5*sum_j tanh(5*(x_j - x_i))
// tanh(5d) = d/L + sum_m beta_m sin(pi*m*d/L), L=8, beta_m = pi/(40*sinh(pi^2 m/80))
// Separable: S_m = sum_j sin(w_m x_j), C_m = sum_j cos(w_m x_j) computed once;
// rank_i = 8193 + (Sx - N x_i)/16 + sum_m 0.5*beta_m*(cos(w_m x_i) S_m - sin(w_m x_i) C_m)
// v_sin/v_cos take REVOLUTIONS: rev = fract(m*x/16).

__device__ __forceinline__ void phase1_body(
    const float* __restrict__ pred, const float* __restrict__ target,
    float* __restrict__ ps, float* __restrict__ pc, float* __restrict__ px,
    int b, int tid) {
  const int a  = b >> 7;
  const int jb = b & 127;
  const float* __restrict__ x = a ? target : pred;
  __shared__ float xs[JSL];
  __shared__ float s4[4][M], c4[4][M];
  if (tid < JSL) xs[tid] = x[jb * JSL + tid];
  __syncthreads();
  const int w = tid >> 6, lane = tid & 63;
  const float mf = (float)(lane + 1) * 0.0625f;      // m/(2L)
  float ss = 0.f, cc = 0.f;
  #pragma unroll
  for (int k = 0; k < 32; ++k) {
    float rev = __builtin_amdgcn_fractf(mf * xs[w * 32 + k]);
    ss += __builtin_amdgcn_sinf(rev);
    cc += __builtin_amdgcn_cosf(rev);
  }
  s4[w][lane] = ss; c4[w][lane] = cc;
  __syncthreads();
  if (w == 0) {
    float S = (s4[0][lane] + s4[1][lane]) + (s4[2][lane] + s4[3][lane]);
    float C = (c4[0][lane] + c4[1][lane]) + (c4[2][lane] + c4[3][lane]);
    ps[(a * M + lane) * JB + jb] = S;                // [a][m][jb]
    pc[(a * M + lane) * JB + jb] = C;
  } else if (w == 1) {                               // block x-sum (linear term)
    float t = xs[lane] + xs[lane + 64];
    #pragma unroll
    for (int off = 32; off; off >>= 1) t += __shfl_down(t, off);
    if (lane == 0) px[a * JB + jb] = t;
  }
}

__device__ __forceinline__ void phase2_body(
    const float* __restrict__ pred, const float* __restrict__ target,
    const float* __restrict__ ps, const float* __restrict__ pc,
    const float* __restrict__ px, double* __restrict__ mom,
    int* __restrict__ counter, float* __restrict__ out,
    int b, int tid) {
  __shared__ float2 sCTS[2][M];
  __shared__ float  shT[2][M], shC[2][M];
  __shared__ float  sSx[2];
  {
    const int which = tid >> 7;                      // 0: sin sums (ps), 1: cos (pc)
    const int aa = (tid >> 6) & 1;
    const int mm = tid & 63;
    const float4* __restrict__ row =
        (const float4*)((which ? pc : ps) + (aa * M + mm) * JB);
    float4 a4 = {0.f, 0.f, 0.f, 0.f};
    #pragma unroll 8
    for (int q = 0; q < JB / 4; ++q) {
      float4 v = row[q];
      a4.x += v.x; a4.y += v.y; a4.z += v.z; a4.w += v.w;
    }
    float s = (a4.x + a4.y) + (a4.z + a4.w);
    if (which) shC[aa][mm] = s; else shT[aa][mm] = s;
    if (tid < 128) {                                 // Sx per array
      const int a2 = tid >> 6, l2 = tid & 63;
      float t = px[a2 * JB + l2] + px[a2 * JB + 64 + l2];
      #pragma unroll
      for (int off = 32; off; off >>= 1) t += __shfl_down(t, off);
      if (l2 == 0) sSx[a2] = t;
    }
  }
  __syncthreads();
  if (tid < 2 * M) {
    const int aa = tid >> 6, mm = tid & 63;
    const float t    = 0.123370055013617f * (float)(mm + 1);   // pi^2*m/80
    const float e    = __expf(t);
    const float beta = 3.14159265358979f / (20.0f * (e - 1.0f / e)); // pi/(40 sinh t)
    sCTS[aa][mm] = make_float2(0.5f * beta * shT[aa][mm],
                               -0.5f * beta * shC[aa][mm]);
  }
  __syncthreads();

  const int a  = tid >> 7;                           // array
  const int mh = (tid >> 6) & 1;                     // mode half
  const int li = tid & 63;                           // i within block
  const int i  = b * I2 + li;
  const float xi = (a ? target : pred)[i];
  float acc = 0.f;
  #pragma unroll
  for (int k = 0; k < 32; ++k) {
    const int m = mh * 32 + k + 1;
    const float2 c = sCTS[a][m - 1];
    float rev = __builtin_amdgcn_fractf((float)m * 0.0625f * xi);
    acc = fmaf(__builtin_amdgcn_cosf(rev), c.x, acc);
    acc = fmaf(__builtin_amdgcn_sinf(rev), c.y, acc);
  }
  __shared__ float shAcc[2][2][I2];
  __shared__ float rk[2][I2];
  shAcc[a][mh][li] = acc;
  __syncthreads();
  if (mh == 0) {
    float at = shAcc[a][0][li] + shAcc[a][1][li];
    rk[a][li] = 8193.0f + 0.0625f * (sSx[a] - 16384.0f * xi) + at;
  }
  __syncthreads();
  if (tid < 64) {                                    // block moments (one wave)
    double p = (double)rk[0][tid], t = (double)rk[1][tid];
    double v[5] = {p, t, p * p, t * t, p * t};
    #pragma unroll
    for (int off = 32; off; off >>= 1) {
      #pragma unroll
      for (int k2 = 0; k2 < 5; ++k2) v[k2] += __shfl_down(v[k2], off);
    }
    if (tid == 0) {
      #pragma unroll
      for (int k2 = 0; k2 < 5; ++k2) mom[b * 5 + k2] = v[k2];
    }
  }

  __shared__ int lastFlag;
  if (tid == 0) {
    __threadfence();
    int prev = __hip_atomic_fetch_add(counter, 1, __ATOMIC_ACQ_REL,
                                      __HIP_MEMORY_SCOPE_AGENT);
    lastFlag = (prev == GB - 1);
  }
  __syncthreads();
  if (lastFlag) {                                    // deterministic tree finalize
    __shared__ double sh[5][GB];
    #pragma unroll
    for (int k2 = 0; k2 < 5; ++k2)
      sh[k2][tid] = __hip_atomic_load(&mom[tid * 5 + k2], __ATOMIC_RELAXED,
                                      __HIP_MEMORY_SCOPE_AGENT);
    __syncthreads();
    for (int s = GB / 2; s > 0; s >>= 1) {
      if (tid < s) {
        #pragma unroll
        for (int k2 = 0; k2 < 5; ++k2) sh[k2][tid] += sh[k2][tid + s];
      }
      __syncthreads();
    }
    if (tid == 0) {
      const double n  = (double)N;
      const double mp = sh[0][0] / n;
      const double mt = sh[1][0] / n;
      const double cov  = sh[4][0] / n - mp * mt;
      const double varp = sh[2][0] / n - mp * mp;
      const double vart = sh[3][0] / n - mt * mt;
      const double corr = cov / (sqrt(varp + 1e-8) * sqrt(vart + 1e-8));
      out[0] = (float)(1.0 - corr);
    }
  }
}

__global__ __launch_bounds__(256) void fused(
    const float* __restrict__ pred, const float* __restrict__ target,
    float* __restrict__ ps, float* __restrict__ pc, float* __restrict__ px,
    double* __restrict__ mom, int* __restrict__ counter,
    float* __restrict__ out) {
  const int tid = threadIdx.x, b = blockIdx.x;
  if (b == 0 && tid == 0) *counter = 0;   // before grid.sync: race-free reset
  phase1_body(pred, target, ps, pc, px, b, tid);
  cg::this_grid().sync();
  phase2_body(pred, target, ps, pc, px, mom, counter, out, b, tid);
}

// ---- fallback path (plain launches), identical math ----
__global__ __launch_bounds__(256) void k1(
    const float* __restrict__ pred, const float* __restrict__ target,
    float* __restrict__ ps, float* __restrict__ pc, float* __restrict__ px,
    int* __restrict__ counter) {
  if (blockIdx.x == 0 && threadIdx.x == 0) *counter = 0;
  phase1_body(pred, target, ps, pc, px, blockIdx.x, threadIdx.x);
}
__global__ __launch_bounds__(256) void k2(
    const float* __restrict__ pred, const float* __restrict__ target,
    const float* __restrict__ ps, const float* __restrict__ pc,
    const float* __restrict__ px, double* __restrict__ mom,
    int* __restrict__ counter, float* __restrict__ out) {
  phase2_body(pred, target, ps, pc, px, mom, counter, out,
              blockIdx.x, threadIdx.x);
}

extern "C" void kernel_launch(void* const* d_in, const int* in_sizes, int n_in,
                              void* d_out, int out_size, void* d_ws, size_t ws_size,
                              hipStream_t stream) {
  const float* pred   = (const float*)d_in[0];
  const float* target = (const float*)d_in[1];
  float* out = (float*)d_out;

  // ws: mom[GB*5] f64 | ps[2*M*JB] f32 | pc[2*M*JB] f32 | px[2*JB] f32 | counter
  double* mom     = (double*)d_ws;
  float*  ps      = (float*)((char*)d_ws + GB * 5 * sizeof(double));
  float*  pc      = ps + 2 * M * JB;
  float*  px      = pc + 2 * M * JB;
  int*    counter = (int*)(px + 2 * JB);

  void* args[] = {(void*)&pred, (void*)&target, (void*)&ps, (void*)&pc,
                  (void*)&px, (void*)&mom, (void*)&counter, (void*)&out};
  hipError_t e = hipLaunchCooperativeKernel((const void*)fused, dim3(GB),
                                            dim3(256), args, 0, stream);
  if (e != hipSuccess) {
    (void)hipGetLastError();               // clear, use plain-launch fallback
    k1<<<GB, 256, 0, stream>>>(pred, target, ps, pc, px, counter);
    k2<<<GB, 256, 0, stream>>>(pred, target, ps, pc, px, mom, counter, out);
  }
}

// Round 8
// 53.904 us; speedup vs baseline: 1.0067x; 1.0067x over previous
//
#include <hip/hip_runtime.h>

#define N   16384
#define M   64        // Fourier modes
#define JB  128       // j-blocks per array (phase 1)
#define JSL 128       // j's per phase-1 block
#define GB  256       // grid blocks
#define I2  64        // i's per block (phase 2)

// rank_i = 1 + N/2 + 0.5*sum_j tanh(5*(x_j - x_i))
// tanh(5d) = d/L + sum_m beta_m sin(pi*m*d/L), L=8, beta_m = pi/(40*sinh(pi^2 m/80))
// Separable: S_m = sum_j sin(w_m x_j), C_m = sum_j cos(w_m x_j) computed once;
// rank_i = 8193 + (Sx - N x_i)/16 + sum_m 0.5*beta_m*(cos(w_m x_i) S_m - sin(w_m x_i) C_m)
// v_sin/v_cos take REVOLUTIONS: rev = fract(m*x/16).

__device__ __forceinline__ void phase1_body(
    const float* __restrict__ pred, const float* __restrict__ target,
    float* __restrict__ ps, float* __restrict__ pc, float* __restrict__ px,
    int b, int tid) {
  const int a  = b >> 7;
  const int jb = b & 127;
  const float* __restrict__ x = a ? target : pred;
  __shared__ float xs[JSL];
  __shared__ float s4[4][M], c4[4][M];
  if (tid < JSL) xs[tid] = x[jb * JSL + tid];
  __syncthreads();
  const int w = tid >> 6, lane = tid & 63;
  const float mf = (float)(lane + 1) * 0.0625f;      // m/(2L)
  float ss = 0.f, cc = 0.f;
  #pragma unroll
  for (int k = 0; k < 32; ++k) {
    float rev = __builtin_amdgcn_fractf(mf * xs[w * 32 + k]);
    ss += __builtin_amdgcn_sinf(rev);
    cc += __builtin_amdgcn_cosf(rev);
  }
  s4[w][lane] = ss; c4[w][lane] = cc;
  __syncthreads();
  if (w == 0) {
    float S = (s4[0][lane] + s4[1][lane]) + (s4[2][lane] + s4[3][lane]);
    float C = (c4[0][lane] + c4[1][lane]) + (c4[2][lane] + c4[3][lane]);
    ps[(a * M + lane) * JB + jb] = S;                // [a][m][jb]
    pc[(a * M + lane) * JB + jb] = C;
  } else if (w == 1) {                               // block x-sum (linear term)
    float t = xs[lane] + xs[lane + 64];
    #pragma unroll
    for (int off = 32; off; off >>= 1) t += __shfl_down(t, off);
    if (lane == 0) px[a * JB + jb] = t;
  }
}

__device__ __forceinline__ void phase2_body(
    const float* __restrict__ pred, const float* __restrict__ target,
    const float* __restrict__ ps, const float* __restrict__ pc,
    const float* __restrict__ px, double* __restrict__ mom,
    int* __restrict__ counter, float* __restrict__ out,
    int b, int tid) {
  __shared__ float2 sCTS[2][M];
  __shared__ float  shT[2][M], shC[2][M];
  __shared__ float  sSx[2];
  {
    const int which = tid >> 7;                      // 0: sin sums (ps), 1: cos (pc)
    const int aa = (tid >> 6) & 1;
    const int mm = tid & 63;
    const float4* __restrict__ row =
        (const float4*)((which ? pc : ps) + (aa * M + mm) * JB);
    float4 a4 = {0.f, 0.f, 0.f, 0.f};
    #pragma unroll 8
    for (int q = 0; q < JB / 4; ++q) {
      float4 v = row[q];
      a4.x += v.x; a4.y += v.y; a4.z += v.z; a4.w += v.w;
    }
    float s = (a4.x + a4.y) + (a4.z + a4.w);
    if (which) shC[aa][mm] = s; else shT[aa][mm] = s;
    if (tid < 128) {                                 // Sx per array
      const int a2 = tid >> 6, l2 = tid & 63;
      float t = px[a2 * JB + l2] + px[a2 * JB + 64 + l2];
      #pragma unroll
      for (int off = 32; off; off >>= 1) t += __shfl_down(t, off);
      if (l2 == 0) sSx[a2] = t;
    }
  }
  __syncthreads();
  if (tid < 2 * M) {
    const int aa = tid >> 6, mm = tid & 63;
    const float t    = 0.123370055013617f * (float)(mm + 1);   // pi^2*m/80
    const float e    = __expf(t);
    const float beta = 3.14159265358979f / (20.0f * (e - 1.0f / e)); // pi/(40 sinh t)
    sCTS[aa][mm] = make_float2(0.5f * beta * shT[aa][mm],
                               -0.5f * beta * shC[aa][mm]);
  }
  __syncthreads();

  const int a  = tid >> 7;                           // array
  const int mh = (tid >> 6) & 1;                     // mode half
  const int li = tid & 63;                           // i within block
  const int i  = b * I2 + li;
  const float xi = (a ? target : pred)[i];
  float acc = 0.f;
  #pragma unroll
  for (int k = 0; k < 32; ++k) {
    const int m = mh * 32 + k + 1;
    const float2 c = sCTS[a][m - 1];
    float rev = __builtin_amdgcn_fractf((float)m * 0.0625f * xi);
    acc = fmaf(__builtin_amdgcn_cosf(rev), c.x, acc);
    acc = fmaf(__builtin_amdgcn_sinf(rev), c.y, acc);
  }
  __shared__ float shAcc[2][2][I2];
  __shared__ float rk[2][I2];
  shAcc[a][mh][li] = acc;
  __syncthreads();
  if (mh == 0) {
    float at = shAcc[a][0][li] + shAcc[a][1][li];
    rk[a][li] = 8193.0f + 0.0625f * (sSx[a] - 16384.0f * xi) + at;
  }
  __syncthreads();
  if (tid < 64) {                                    // block moments (one wave)
    double p = (double)rk[0][tid], t = (double)rk[1][tid];
    double v[5] = {p, t, p * p, t * t, p * t};
    #pragma unroll
    for (int off = 32; off; off >>= 1) {
      #pragma unroll
      for (int k2 = 0; k2 < 5; ++k2) v[k2] += __shfl_down(v[k2], off);
    }
    if (tid == 0) {
      #pragma unroll
      for (int k2 = 0; k2 < 5; ++k2) mom[b * 5 + k2] = v[k2];
    }
  }

  __shared__ int lastFlag;
  if (tid == 0) {
    __threadfence();
    int prev = __hip_atomic_fetch_add(counter, 1, __ATOMIC_ACQ_REL,
                                      __HIP_MEMORY_SCOPE_AGENT);
    lastFlag = (prev == GB - 1);
  }
  __syncthreads();
  if (lastFlag) {                                    // deterministic tree finalize
    __shared__ double sh[5][GB];
    #pragma unroll
    for (int k2 = 0; k2 < 5; ++k2)
      sh[k2][tid] = __hip_atomic_load(&mom[tid * 5 + k2], __ATOMIC_RELAXED,
                                      __HIP_MEMORY_SCOPE_AGENT);
    __syncthreads();
    for (int s = GB / 2; s > 0; s >>= 1) {
      if (tid < s) {
        #pragma unroll
        for (int k2 = 0; k2 < 5; ++k2) sh[k2][tid] += sh[k2][tid + s];
      }
      __syncthreads();
    }
    if (tid == 0) {
      const double n  = (double)N;
      const double mp = sh[0][0] / n;
      const double mt = sh[1][0] / n;
      const double cov  = sh[4][0] / n - mp * mt;
      const double varp = sh[2][0] / n - mp * mp;
      const double vart = sh[3][0] / n - mt * mt;
      const double corr = cov / (sqrt(varp + 1e-8) * sqrt(vart + 1e-8));
      out[0] = (float)(1.0 - corr);
    }
  }
}

__global__ void init_barrier(int* __restrict__ bar) {
  bar[0] = 0;   // phase barrier counter
  bar[1] = 0;   // finalize counter
}

__global__ __launch_bounds__(256) void fused(
    const float* __restrict__ pred, const float* __restrict__ target,
    float* __restrict__ ps, float* __restrict__ pc, float* __restrict__ px,
    double* __restrict__ mom, int* __restrict__ bar,
    float* __restrict__ out) {
  const int tid = threadIdx.x, b = blockIdx.x;

  phase1_body(pred, target, ps, pc, px, b, tid);

  // ---- lightweight grid barrier (release/acquire, agent scope) ----
  // All 256 blocks are co-resident by construction (256 blocks x 4 waves,
  // 8-block/CU capacity on 256 CUs) -> spin cannot deadlock.
  if (tid == 0) {
    __threadfence();                                  // release phase-1 stores
    __hip_atomic_fetch_add(&bar[0], 1, __ATOMIC_ACQ_REL,
                           __HIP_MEMORY_SCOPE_AGENT);
    while (__hip_atomic_load(&bar[0], __ATOMIC_RELAXED,
                             __HIP_MEMORY_SCOPE_AGENT) != GB) {
      __builtin_amdgcn_s_sleep(2);
    }
    __threadfence();                                  // acquire phase-1 stores
  }
  __syncthreads();

  phase2_body(pred, target, ps, pc, px, mom, &bar[1], out, b, tid);
}

extern "C" void kernel_launch(void* const* d_in, const int* in_sizes, int n_in,
                              void* d_out, int out_size, void* d_ws, size_t ws_size,
                              hipStream_t stream) {
  const float* pred   = (const float*)d_in[0];
  const float* target = (const float*)d_in[1];
  float* out = (float*)d_out;

  // ws: mom[GB*5] f64 | ps[2*M*JB] f32 | pc[2*M*JB] f32 | px[2*JB] f32 | bar[2]
  double* mom = (double*)d_ws;
  float*  ps  = (float*)((char*)d_ws + GB * 5 * sizeof(double));
  float*  pc  = ps + 2 * M * JB;
  float*  px  = pc + 2 * M * JB;
  int*    bar = (int*)(px + 2 * JB);

  init_barrier<<<1, 1, 0, stream>>>(bar);
  fused<<<GB, 256, 0, stream>>>(pred, target, ps, pc, px, mom, bar, out);
}

// Round 9
// 39.573 us; speedup vs baseline: 1.3712x; 1.3621x over previous
//
#include <hip/hip_runtime.h>

#define N   16384
#define M   64        // Fourier modes
#define JB  128       // j-columns per array (phase-1 block = (a, jb))
#define JSL 128       // j's per phase-1 block
#define GB  256       // grid blocks
#define I2  64        // i's per block (phase 2)

// rank_i = 1 + N/2 + 0.5*sum_j tanh(5*(x_j - x_i))
// tanh(5d) = d/L + sum_m beta_m sin(pi*m*d/L), L=8, beta_m = pi/(40*sinh(pi^2 m/80))
// S_m = sum_j sin(w_m x_j), C_m = sum_j cos(w_m x_j) once; then
// rank_i = 8193 + Sx/16 - 1024*x_i + sum_m 0.5*beta_m*(cos(w_m x_i) S_m - sin(w_m x_i) C_m)
// All cross-block data moves through LLC via relaxed agent-scope atomics
// (bypass L2) -- NO acquire fences (no buffer_inv storms; see R8 post-mortem).

__device__ __forceinline__ void ast_f(float* p, float v) {
  __hip_atomic_store(p, v, __ATOMIC_RELAXED, __HIP_MEMORY_SCOPE_AGENT);
}
__device__ __forceinline__ float2 ald_f2(const float2* p) {
  unsigned long long u = __hip_atomic_load((const unsigned long long*)p,
                                           __ATOMIC_RELAXED, __HIP_MEMORY_SCOPE_AGENT);
  return __builtin_bit_cast(float2, u);
}
__device__ __forceinline__ void ast_f2(float2* p, float2 v) {
  __hip_atomic_store((unsigned long long*)p, __builtin_bit_cast(unsigned long long, v),
                     __ATOMIC_RELAXED, __HIP_MEMORY_SCOPE_AGENT);
}
__device__ __forceinline__ double ald_d(const double* p) {
  return __hip_atomic_load(p, __ATOMIC_RELAXED, __HIP_MEMORY_SCOPE_AGENT);
}
__device__ __forceinline__ void ast_d(double* p, double v) {
  __hip_atomic_store(p, v, __ATOMIC_RELAXED, __HIP_MEMORY_SCOPE_AGENT);
}

__global__ void init_bar(int* __restrict__ bar) {
  bar[0] = 0;   // phase-1 arrival counter
  bar[1] = 0;   // coefficients-ready flag
  bar[2] = 0;   // finalize counter
}

__global__ __launch_bounds__(256) void fused(
    const float* __restrict__ pred, const float* __restrict__ target,
    float* __restrict__ ps, float* __restrict__ pc, float* __restrict__ px,
    float2* __restrict__ coef,        // [0..127]=(a*64+m) coeffs, [128]=(K_p,K_t)
    double* __restrict__ mom, int* __restrict__ bar,
    float* __restrict__ out) {
  const int tid = threadIdx.x, b = blockIdx.x;

  // ---------------- phase 1: per-(array, j-chunk) mode partials ----------------
  const int a  = b >> 7;
  const int jb = b & 127;
  const float* __restrict__ x = a ? target : pred;
  __shared__ float xs[JSL];
  __shared__ float s4[4][M], c4[4][M];
  if (tid < JSL) xs[tid] = x[jb * JSL + tid];
  __syncthreads();
  const int w = tid >> 6, lane = tid & 63;
  {
    const float mf = (float)(lane + 1) * 0.0625f;    // m/(2L)
    float ss = 0.f, cc = 0.f;
    #pragma unroll
    for (int k = 0; k < 32; ++k) {
      float rev = __builtin_amdgcn_fractf(mf * xs[w * 32 + k]);
      ss += __builtin_amdgcn_sinf(rev);
      cc += __builtin_amdgcn_cosf(rev);
    }
    s4[w][lane] = ss; c4[w][lane] = cc;
  }
  __syncthreads();
  if (w == 0) {
    float S = (s4[0][lane] + s4[1][lane]) + (s4[2][lane] + s4[3][lane]);
    float C = (c4[0][lane] + c4[1][lane]) + (c4[2][lane] + c4[3][lane]);
    ast_f(&ps[(a * M + lane) * JB + jb], S);
    ast_f(&pc[(a * M + lane) * JB + jb], C);
  } else if (w == 1) {
    float t = xs[lane] + xs[lane + 64];
    #pragma unroll
    for (int off = 32; off; off >>= 1) t += __shfl_down(t, off);
    if (lane == 0) ast_f(&px[a * JB + jb], t);
  }
  __syncthreads();   // compiler drains vmcnt before s_barrier -> stores complete

  // ---------------- arrival; last block builds the coefficient table ----------
  __shared__ int lastArr;
  if (tid == 0) {
    int prev = __hip_atomic_fetch_add(&bar[0], 1, __ATOMIC_ACQ_REL,
                                      __HIP_MEMORY_SCOPE_AGENT);
    lastArr = (prev == GB - 1);
  }
  __syncthreads();
  if (lastArr) {
    __shared__ float rT[2][M], rC[2][M];
    __shared__ float rSx[2];
    const int which = tid >> 7, aa = (tid >> 6) & 1, mm = tid & 63;
    const float2* __restrict__ row =
        (const float2*)((which ? pc : ps) + (aa * M + mm) * JB);
    float s = 0.f;
    #pragma unroll 8
    for (int q = 0; q < JB / 2; ++q) { float2 v = ald_f2(row + q); s += v.x + v.y; }
    if (which) rC[aa][mm] = s; else rT[aa][mm] = s;
    if (tid < 2) {
      const float2* __restrict__ prow = (const float2*)(px + tid * JB);
      float t = 0.f;
      #pragma unroll 8
      for (int q = 0; q < JB / 2; ++q) { float2 v = ald_f2(prow + q); t += v.x + v.y; }
      rSx[tid] = t;
    }
    __syncthreads();
    if (tid < 2 * M) {
      const int a2 = tid >> 6, m2 = tid & 63;
      const float t    = 0.123370055013617f * (float)(m2 + 1);     // pi^2*m/80
      const float e    = __expf(t);
      const float beta = 3.14159265358979f / (20.0f * (e - 1.0f / e)); // pi/(40 sinh t)
      ast_f2(&coef[a2 * M + m2], make_float2(0.5f * beta * rT[a2][m2],
                                             -0.5f * beta * rC[a2][m2]));
    }
    if (tid == 0)
      ast_f2(&coef[128], make_float2(8193.0f + 0.0625f * rSx[0],
                                     8193.0f + 0.0625f * rSx[1]));
    __syncthreads();   // drain coef stores (vmcnt(0) before s_barrier)
    if (tid == 0)
      __hip_atomic_store(&bar[1], 1, __ATOMIC_RELEASE, __HIP_MEMORY_SCOPE_AGENT);
  }

  // ---------------- wait for coefficients (relaxed spin, no acquire fence) ----
  if (tid == 0) {
    while (__hip_atomic_load(&bar[1], __ATOMIC_RELAXED,
                             __HIP_MEMORY_SCOPE_AGENT) == 0) {
      __builtin_amdgcn_s_sleep(8);
    }
  }
  __syncthreads();
  asm volatile("" ::: "memory");   // compile-time ordering only

  __shared__ float2 sCoef[129];
  if (tid < 129) sCoef[tid] = ald_f2(&coef[tid]);
  __syncthreads();

  // ---------------- phase 2: ranks + block moments (verbatim R8 math) --------
  const int aa2 = tid >> 7;                 // array
  const int mh  = (tid >> 6) & 1;           // mode half
  const int li  = tid & 63;                 // i within block
  const int i   = b * I2 + li;
  const float xi = (aa2 ? target : pred)[i];
  float acc = 0.f;
  #pragma unroll
  for (int k = 0; k < 32; ++k) {
    const int m = mh * 32 + k + 1;
    const float2 c = sCoef[aa2 * M + m - 1];
    float rev = __builtin_amdgcn_fractf((float)m * 0.0625f * xi);
    acc = fmaf(__builtin_amdgcn_cosf(rev), c.x, acc);
    acc = fmaf(__builtin_amdgcn_sinf(rev), c.y, acc);
  }
  __shared__ float shAcc[2][2][I2];
  __shared__ float rk[2][I2];
  shAcc[aa2][mh][li] = acc;
  __syncthreads();
  if (mh == 0) {
    float at = shAcc[aa2][0][li] + shAcc[aa2][1][li];
    const float K = aa2 ? sCoef[128].y : sCoef[128].x;
    rk[aa2][li] = K - 1024.0f * xi + at;
  }
  __syncthreads();
  if (tid < 64) {
    double p = (double)rk[0][tid], t = (double)rk[1][tid];
    double v[5] = {p, t, p * p, t * t, p * t};
    #pragma unroll
    for (int off = 32; off; off >>= 1) {
      #pragma unroll
      for (int k2 = 0; k2 < 5; ++k2) v[k2] += __shfl_down(v[k2], off);
    }
    if (tid == 0) {
      #pragma unroll
      for (int k2 = 0; k2 < 5; ++k2) ast_d(&mom[b * 5 + k2], v[k2]);
    }
  }
  __syncthreads();   // drain mom stores before signaling

  // ---------------- finalize (R6-proven pattern, no acquire fence) -----------
  __shared__ int lastFin;
  if (tid == 0) {
    int prev = __hip_atomic_fetch_add(&bar[2], 1, __ATOMIC_ACQ_REL,
                                      __HIP_MEMORY_SCOPE_AGENT);
    lastFin = (prev == GB - 1);
  }
  __syncthreads();
  if (lastFin) {
    __shared__ double sh[5][GB];
    #pragma unroll
    for (int k2 = 0; k2 < 5; ++k2) sh[k2][tid] = ald_d(&mom[tid * 5 + k2]);
    __syncthreads();
    for (int s = GB / 2; s > 0; s >>= 1) {
      if (tid < s) {
        #pragma unroll
        for (int k2 = 0; k2 < 5; ++k2) sh[k2][tid] += sh[k2][tid + s];
      }
      __syncthreads();
    }
    if (tid == 0) {
      const double n  = (double)N;
      const double mp = sh[0][0] / n;
      const double mt = sh[1][0] / n;
      const double cov  = sh[4][0] / n - mp * mt;
      const double varp = sh[2][0] / n - mp * mp;
      const double vart = sh[3][0] / n - mt * mt;
      const double corr = cov / (sqrt(varp + 1e-8) * sqrt(vart + 1e-8));
      out[0] = (float)(1.0 - corr);
    }
  }
}

extern "C" void kernel_launch(void* const* d_in, const int* in_sizes, int n_in,
                              void* d_out, int out_size, void* d_ws, size_t ws_size,
                              hipStream_t stream) {
  const float* pred   = (const float*)d_in[0];
  const float* target = (const float*)d_in[1];
  float* out = (float*)d_out;

  // ws: mom[GB*5] f64 | coef[130] float2 | ps[2*M*JB] | pc[2*M*JB] | px[2*JB] | bar[3]
  double* mom  = (double*)d_ws;
  float2* coef = (float2*)((char*)d_ws + GB * 5 * sizeof(double));
  float*  ps   = (float*)(coef + 130);
  float*  pc   = ps + 2 * M * JB;
  float*  px   = pc + 2 * M * JB;
  int*    bar  = (int*)(px + 2 * JB);

  init_bar<<<1, 1, 0, stream>>>(bar);
  fused<<<GB, 256, 0, stream>>>(pred, target, ps, pc, px, coef, mom, bar, out);
}

// Round 10
// 18.892 us; speedup vs baseline: 2.8722x; 2.0947x over previous
//
#include <hip/hip_runtime.h>

#define N    16384
#define M    64        // Fourier modes (lane = m-1)
#define JBC  32        // j-chunks per array (K1 grid.x)
#define JSL  512       // j's per chunk
#define K2B  64        // K2 blocks
#define I2   256       // i's per K2 block

// rank_i = 1 + N/2 + 0.5*sum_j tanh(5*(x_j - x_i))
// tanh(5d) = d/L + sum_m beta_m sin(pi*m*d/L), L=8, beta_m = pi/(40*sinh(pi^2 m/80))
// S_m = sum_j sin(w_m x_j), C_m = sum_j cos(w_m x_j) once; then
// rank_i = [8193 + Sx/16] - 1024*x_i + sum_m 0.5*beta_m*(cos(w_m x_i) S_m - sin(w_m x_i) C_m)
// v_sin/v_cos take REVOLUTIONS: rev = fract(m*x/16).

__device__ __forceinline__ double ald_d(const double* p) {
  return __hip_atomic_load(p, __ATOMIC_RELAXED, __HIP_MEMORY_SCOPE_AGENT);
}
__device__ __forceinline__ void ast_d(double* p, double v) {
  __hip_atomic_store(p, v, __ATOMIC_RELAXED, __HIP_MEMORY_SCOPE_AGENT);
}

__global__ __launch_bounds__(256) void k1_freq(
    const float* __restrict__ pred, const float* __restrict__ target,
    float* __restrict__ ps, float* __restrict__ pc, float* __restrict__ px,
    int* __restrict__ bar) {
  const int a   = blockIdx.y;               // 0 = pred, 1 = target
  const int jb  = blockIdx.x;               // 0..JBC-1
  const int tid = threadIdx.x;
  if (a == 0 && jb == 0 && tid == 0) bar[0] = 0;   // reset K2 finalize counter

  const float* __restrict__ x = a ? target : pred;
  __shared__ float xs[JSL];
  __shared__ float s4[4][M], c4[4][M];
  xs[tid]       = x[jb * JSL + tid];
  xs[tid + 256] = x[jb * JSL + 256 + tid];
  __syncthreads();

  const int w = tid >> 6, lane = tid & 63;
  const float mf = (float)(lane + 1) * 0.0625f;    // m/(2L)
  const float* __restrict__ xh = xs + w * 128;
  float ss = 0.f, cc = 0.f;
  #pragma unroll 8
  for (int k = 0; k < 128; ++k) {
    float rev = __builtin_amdgcn_fractf(mf * xh[k]);
    ss += __builtin_amdgcn_sinf(rev);
    cc += __builtin_amdgcn_cosf(rev);
  }
  s4[w][lane] = ss; c4[w][lane] = cc;
  __syncthreads();
  if (w == 0) {
    float S = (s4[0][lane] + s4[1][lane]) + (s4[2][lane] + s4[3][lane]);
    float C = (c4[0][lane] + c4[1][lane]) + (c4[2][lane] + c4[3][lane]);
    ps[(a * M + lane) * JBC + jb] = S;             // [a][m][jb]
    pc[(a * M + lane) * JBC + jb] = C;
  } else if (w == 1) {                             // chunk x-sum (linear term)
    float t = 0.f;
    #pragma unroll
    for (int k = 0; k < 8; ++k) t += xs[lane + 64 * k];
    #pragma unroll
    for (int off = 32; off; off >>= 1) t += __shfl_down(t, off);
    if (lane == 0) px[a * JBC + jb] = t;
  }
}

__global__ __launch_bounds__(256) void k2_rank(
    const float* __restrict__ pred, const float* __restrict__ target,
    const float* __restrict__ ps, const float* __restrict__ pc,
    const float* __restrict__ px, double* __restrict__ mom,
    int* __restrict__ bar, float* __restrict__ out) {
  const int tid = threadIdx.x, b = blockIdx.x;

  __shared__ float2 sCTS[2][M];
  __shared__ float  sK[2];
  __shared__ float  shT[2][M], shC[2][M];
  {
    const int which = tid >> 7;                    // 0: sin sums (ps), 1: cos (pc)
    const int aa = (tid >> 6) & 1;
    const int mm = tid & 63;
    const float4* __restrict__ row =
        (const float4*)((which ? pc : ps) + (aa * M + mm) * JBC);
    float4 a4 = {0.f, 0.f, 0.f, 0.f};
    #pragma unroll
    for (int q = 0; q < JBC / 4; ++q) {
      float4 v = row[q];
      a4.x += v.x; a4.y += v.y; a4.z += v.z; a4.w += v.w;
    }
    float s = (a4.x + a4.y) + (a4.z + a4.w);
    if (which) shC[aa][mm] = s; else shT[aa][mm] = s;
    if (tid < 2) {
      const float4* __restrict__ prow = (const float4*)(px + tid * JBC);
      float4 t4 = {0.f, 0.f, 0.f, 0.f};
      #pragma unroll
      for (int q = 0; q < JBC / 4; ++q) {
        float4 v = prow[q];
        t4.x += v.x; t4.y += v.y; t4.z += v.z; t4.w += v.w;
      }
      sK[tid] = 8193.0f + 0.0625f * ((t4.x + t4.y) + (t4.z + t4.w));
    }
  }
  __syncthreads();
  if (tid < 2 * M) {
    const int a2 = tid >> 6, m2 = tid & 63;
    const float t    = 0.123370055013617f * (float)(m2 + 1);       // pi^2*m/80
    const float e    = __expf(t);
    const float beta = 3.14159265358979f / (20.0f * (e - 1.0f / e)); // pi/(40 sinh t)
    sCTS[a2][m2] = make_float2(0.5f * beta * shT[a2][m2],
                               -0.5f * beta * shC[a2][m2]);
  }
  __syncthreads();

  const int a  = tid >> 7;                         // array
  const int li = tid & 127;
  const float* __restrict__ xa = a ? target : pred;
  __shared__ float rk[2][I2];
  #pragma unroll
  for (int p2 = 0; p2 < 2; ++p2) {
    const int i = b * I2 + p2 * 128 + li;
    const float xi = xa[i];
    float acc = 0.f;
    #pragma unroll 8
    for (int m = 1; m <= M; ++m) {
      const float2 c = sCTS[a][m - 1];
      float rev = __builtin_amdgcn_fractf((float)m * 0.0625f * xi);
      acc = fmaf(__builtin_amdgcn_cosf(rev), c.x, acc);
      acc = fmaf(__builtin_amdgcn_sinf(rev), c.y, acc);
    }
    rk[a][p2 * 128 + li] = sK[a] - 1024.0f * xi + acc;
  }
  __syncthreads();

  __shared__ double wsum[2][5];
  if (tid < 128) {                                 // block moments, 2 waves
    double p0 = (double)rk[0][tid],       t0 = (double)rk[1][tid];
    double p1 = (double)rk[0][tid + 128], t1 = (double)rk[1][tid + 128];
    double v[5] = {p0 + p1, t0 + t1, p0*p0 + p1*p1, t0*t0 + t1*t1, p0*t0 + p1*t1};
    #pragma unroll
    for (int off = 32; off; off >>= 1) {
      #pragma unroll
      for (int k = 0; k < 5; ++k) v[k] += __shfl_down(v[k], off);
    }
    if ((tid & 63) == 0) {
      #pragma unroll
      for (int k = 0; k < 5; ++k) wsum[tid >> 6][k] = v[k];
    }
  }
  __syncthreads();

  __shared__ int lastFin;
  if (tid == 0) {
    #pragma unroll
    for (int k = 0; k < 5; ++k) ast_d(&mom[b * 5 + k], wsum[0][k] + wsum[1][k]);
    __threadfence();                               // release (cheap; R6-proven)
    int prev = __hip_atomic_fetch_add(&bar[0], 1, __ATOMIC_ACQ_REL,
                                      __HIP_MEMORY_SCOPE_AGENT);
    lastFin = (prev == K2B - 1);
  }
  __syncthreads();
  if (lastFin && tid < 64) {                       // single-wave finalize
    double v[5];
    #pragma unroll
    for (int k = 0; k < 5; ++k) v[k] = ald_d(&mom[tid * 5 + k]);
    #pragma unroll
    for (int off = 32; off; off >>= 1) {
      #pragma unroll
      for (int k = 0; k < 5; ++k) v[k] += __shfl_down(v[k], off);
    }
    if (tid == 0) {
      const double n  = (double)N;
      const double mp = v[0] / n;
      const double mt = v[1] / n;
      const double cov  = v[4] / n - mp * mt;
      const double varp = v[2] / n - mp * mp;
      const double vart = v[3] / n - mt * mt;
      const double corr = cov / (sqrt(varp + 1e-8) * sqrt(vart + 1e-8));
      out[0] = (float)(1.0 - corr);
    }
  }
}

extern "C" void kernel_launch(void* const* d_in, const int* in_sizes, int n_in,
                              void* d_out, int out_size, void* d_ws, size_t ws_size,
                              hipStream_t stream) {
  const float* pred   = (const float*)d_in[0];
  const float* target = (const float*)d_in[1];
  float* out = (float*)d_out;

  // ws: mom[K2B*5] f64 | ps[2*M*JBC] f32 | pc[2*M*JBC] f32 | px[2*JBC] f32 | bar[1]
  double* mom = (double*)d_ws;
  float*  ps  = (float*)((char*)d_ws + K2B * 5 * sizeof(double));
  float*  pc  = ps + 2 * M * JBC;
  float*  px  = pc + 2 * M * JBC;
  int*    bar = (int*)(px + 2 * JBC);

  k1_freq<<<dim3(JBC, 2), 256, 0, stream>>>(pred, target, ps, pc, px, bar);
  k2_rank<<<K2B, 256, 0, stream>>>(pred, target, ps, pc, px, mom, bar, out);
}